// Round 1
// baseline (279.402 us; speedup 1.0000x reference)
//
#include <hip/hip_runtime.h>

typedef short short8 __attribute__((ext_vector_type(8)));
typedef float floatx4 __attribute__((ext_vector_type(4)));

#define T_ROWS 32768
#define C_DIM 512
#define M_DIM 512

__device__ __forceinline__ unsigned short f2bf(float f) {
    unsigned u = __builtin_bit_cast(unsigned, f);
    u = u + 0x7fffu + ((u >> 16) & 1u);
    return (unsigned short)(u >> 16);
}

// ---------------- pack kernel: keys -> B-frag order (score GEMM), values -> B-frag order (PV GEMM)
// B fragment for mfma_f32_16x16x32_bf16: lane l holds B[k = (l>>4)*8 + j][n = l&15], j=0..7
// frag buffer index: ((kt*32 + NT)*64 + l)*8 + j   (kt: K/32 tile, NT: N/16 tile)
__global__ __launch_bounds__(256) void pack_kernel(
    const float* __restrict__ keys, const float* __restrict__ values,
    unsigned short* __restrict__ keysFrag, unsigned short* __restrict__ valsFrag) {
    int tid = blockIdx.x * 256 + threadIdx.x;      // 0..65535
    int e  = tid & 32767;
    int l  = e & 63;
    int NT = (e >> 6) & 31;
    int kt = e >> 11;                               // 0..15
    int li = l & 15, q4 = l >> 4;
    unsigned short tmp[8];
    if (tid < 32768) {
        // score GEMM: B[k][n] = keysT[k][n] = keys[n][k], keys is [M, C] row-major
        const float* s = keys + (size_t)(NT * 16 + li) * C_DIM + kt * 32 + q4 * 8;
#pragma unroll
        for (int j = 0; j < 8; j++) tmp[j] = f2bf(s[j]);
        unsigned short* d = keysFrag + ((size_t)(kt * 32 + NT) * 64 + l) * 8;
        ushort4 a = make_ushort4(tmp[0], tmp[1], tmp[2], tmp[3]);
        ushort4 b = make_ushort4(tmp[4], tmp[5], tmp[6], tmp[7]);
        *(ushort4*)d = a;
        *(ushort4*)(d + 4) = b;
    } else {
        // PV GEMM: B[k][n] = values[k][n], values is [M, C] row-major, k indexes M
#pragma unroll
        for (int j = 0; j < 8; j++)
            tmp[j] = f2bf(values[(size_t)(kt * 32 + q4 * 8 + j) * C_DIM + NT * 16 + li]);
        unsigned short* d = valsFrag + ((size_t)(kt * 32 + NT) * 64 + l) * 8;
        ushort4 a = make_ushort4(tmp[0], tmp[1], tmp[2], tmp[3]);
        ushort4 b = make_ushort4(tmp[4], tmp[5], tmp[6], tmp[7]);
        *(ushort4*)d = a;
        *(ushort4*)(d + 4) = b;
    }
}

// ---------------- fused main kernel: 32 rows per block, 512 threads (8 waves)
// waves: rg = w>>2 (row group 0/1 -> rows rg*16..+15), mc = w&3 (score col chunk mc*128..+127)
__global__ __launch_bounds__(512) void fused_kernel(
    const float* __restrict__ key,
    const unsigned short* __restrict__ keysFrag,
    const unsigned short* __restrict__ valsFrag,
    float* __restrict__ outRQ,
    float* __restrict__ scal,   // [0]=entropy, [1]=gather (unused here), [2]=contrast
    int* __restrict__ idxOut) {
    __shared__ char kq[32 * 1040];              // k bf16 tile, later reused as p tile (rows padded to 1040B)
    __shared__ float stats[2][4][16][8];        // [rg][mc][row_in_group][m,z1,e1,z2,idx]
    __shared__ float finals[32][2];             // [row][m1, 1/z1]

    const int tid = threadIdx.x;
    const int w  = tid >> 6;
    const int l  = tid & 63;
    const int li = l & 15;
    const int q4 = l >> 4;
    const int row0 = blockIdx.x << 5;

    // ---- phase 0: load 4 rows/wave, l2-normalize, write bf16 to LDS ----
    {
        int r = (w << 2) + q4;                                  // row in block; 16 lanes per row
        const float4* src = (const float4*)(key + (size_t)(row0 + r) * C_DIM);
        float4 v[8];
        float ss = 0.f;
#pragma unroll
        for (int i = 0; i < 8; i++) {
            v[i] = src[i * 16 + li];
            ss += v[i].x * v[i].x + v[i].y * v[i].y + v[i].z * v[i].z + v[i].w * v[i].w;
        }
#pragma unroll
        for (int m = 1; m < 16; m <<= 1) ss += __shfl_xor(ss, m, 64);
        float inv = 1.0f / fmaxf(sqrtf(ss), 1e-12f);
        char* dstrow = kq + r * 1040;
#pragma unroll
        for (int i = 0; i < 8; i++) {
            ushort4 b = make_ushort4(f2bf(v[i].x * inv), f2bf(v[i].y * inv),
                                     f2bf(v[i].z * inv), f2bf(v[i].w * inv));
            *(ushort4*)(dstrow + i * 128 + li * 8) = b;
        }
    }
    __syncthreads();

    // ---- phase 1: score GEMM. wave computes rows [rg*16, +16) x cols [mc*128, +128) ----
    const int rg = w >> 2;
    const int mc = w & 3;
    floatx4 acc1[8];
#pragma unroll
    for (int i = 0; i < 8; i++) acc1[i] = (floatx4){0.f, 0.f, 0.f, 0.f};
    const short8* kf = (const short8*)keysFrag;
    for (int kt = 0; kt < 16; kt++) {
        short8 a = *(const short8*)(kq + (rg * 16 + li) * 1040 + kt * 64 + q4 * 16);
#pragma unroll
        for (int nt = 0; nt < 8; nt++) {
            short8 b = kf[(size_t)((kt * 32 + mc * 8 + nt) * 64 + l)];
            acc1[nt] = __builtin_amdgcn_mfma_f32_16x16x32_bf16(a, b, acc1[nt], 0, 0, 0);
        }
    }

    // ---- phase 2: per-row stats. C layout: col = li, row = q4*4 + reg ----
#pragma unroll
    for (int reg = 0; reg < 4; reg++) {
        float m = acc1[0][reg];
        int bi = (mc * 8 + 0) * 16 + li;
#pragma unroll
        for (int nt = 1; nt < 8; nt++) {
            float s = acc1[nt][reg];
            if (s > m) { m = s; bi = (mc * 8 + nt) * 16 + li; }
        }
        float z1 = 0.f, e1 = 0.f, z2 = 0.f;
#pragma unroll
        for (int nt = 0; nt < 8; nt++) {
            float s = acc1[nt][reg];
            float p = __expf(s - m);
            z1 += p; e1 += p * s; z2 += p * p;
        }
#pragma unroll
        for (int msk = 1; msk < 16; msk <<= 1) {
            float mo  = __shfl_xor(m,  msk, 64);
            float z1o = __shfl_xor(z1, msk, 64);
            float e1o = __shfl_xor(e1, msk, 64);
            float z2o = __shfl_xor(z2, msk, 64);
            int   bio = __shfl_xor(bi, msk, 64);
            if (mo > m) {
                float sc = __expf(m - mo);
                z1 = z1 * sc + z1o; e1 = e1 * sc + e1o; z2 = z2 * sc * sc + z2o;
                m = mo; bi = bio;
            } else if (mo == m) {
                z1 += z1o; e1 += e1o; z2 += z2o; bi = min(bi, bio);
            } else {
                float sc = __expf(mo - m);
                z1 += z1o * sc; e1 += e1o * sc; z2 += z2o * sc * sc;
            }
        }
        if (li == 0) {
            float* st = stats[rg][mc][q4 * 4 + reg];
            st[0] = m; st[1] = z1; st[2] = e1; st[3] = z2;
            ((int*)st)[4] = bi;
        }
    }
    __syncthreads();

    if (tid < 32) {
        int r = tid;
        const float* st0 = stats[r >> 4][0][r & 15];
        float m = st0[0], z1 = st0[1], e1 = st0[2], z2 = st0[3];
        int bi = ((const int*)st0)[4];
#pragma unroll
        for (int p = 1; p < 4; p++) {
            const float* st = stats[r >> 4][p][r & 15];
            float mo = st[0], z1o = st[1], e1o = st[2], z2o = st[3];
            int bio = ((const int*)st)[4];
            if (mo > m) {
                float sc = __expf(m - mo);
                z1 = z1 * sc + z1o; e1 = e1 * sc + e1o; z2 = z2 * sc * sc + z2o;
                m = mo; bi = bio;
            } else if (mo == m) {
                z1 += z1o; e1 += e1o; z2 += z2o; bi = min(bi, bio);
            } else {
                float sc = __expf(mo - m);
                z1 += z1o * sc; e1 += e1o * sc; z2 += z2o * sc * sc;
            }
        }
        finals[r][0] = m;
        finals[r][1] = 1.0f / z1;
        idxOut[row0 + r] = bi;
        float ent = m + __logf(z1) - e1 / z1;   // logZ - sum(w*s)
        float con = __logf(z2);                  // -logp[idx] of logits=2s
#pragma unroll
        for (int msk = 1; msk < 32; msk <<= 1) {
            ent += __shfl_xor(ent, msk, 64);
            con += __shfl_xor(con, msk, 64);
        }
        if (tid == 0) {
            atomicAdd(&scal[0], ent * (1.0f / 32768.0f));
            atomicAdd(&scal[2], con * (1.0f / 12800.0f));
        }
    }
    __syncthreads();

    // ---- phase 3: p = e^{s - m1} bf16, overwrite kq (all k reads done) ----
#pragma unroll
    for (int reg = 0; reg < 4; reg++) {
        int r = rg * 16 + q4 * 4 + reg;
        float m1 = finals[r][0];
#pragma unroll
        for (int nt = 0; nt < 8; nt++) {
            float p = __expf(acc1[nt][reg] - m1);
            int col = (mc * 8 + nt) * 16 + li;
            *(unsigned short*)(kq + r * 1040 + col * 2) = f2bf(p);
        }
    }
    __syncthreads();

    // ---- phase 4: PV GEMM. wave computes out cols [w*64, +64), all 32 rows ----
    floatx4 acc2[2][4];
#pragma unroll
    for (int g = 0; g < 2; g++)
#pragma unroll
        for (int nt = 0; nt < 4; nt++) acc2[g][nt] = (floatx4){0.f, 0.f, 0.f, 0.f};
    const short8* vf = (const short8*)valsFrag;
    for (int kt = 0; kt < 16; kt++) {
        short8 a0 = *(const short8*)(kq + li * 1040 + kt * 64 + q4 * 16);
        short8 a1 = *(const short8*)(kq + (16 + li) * 1040 + kt * 64 + q4 * 16);
#pragma unroll
        for (int nt = 0; nt < 4; nt++) {
            short8 b = vf[(size_t)((kt * 32 + w * 4 + nt) * 64 + l)];
            acc2[0][nt] = __builtin_amdgcn_mfma_f32_16x16x32_bf16(a0, b, acc2[0][nt], 0, 0, 0);
            acc2[1][nt] = __builtin_amdgcn_mfma_f32_16x16x32_bf16(a1, b, acc2[1][nt], 0, 0, 0);
        }
    }

    // ---- phase 5: scale by 1/Z1 and store ----
#pragma unroll
    for (int g = 0; g < 2; g++) {
#pragma unroll
        for (int reg = 0; reg < 4; reg++) {
            int r = g * 16 + q4 * 4 + reg;
            float iz = finals[r][1];
            float* orow = outRQ + (size_t)(row0 + r) * C_DIM + w * 64 + li;
#pragma unroll
            for (int nt = 0; nt < 4; nt++) orow[nt * 16] = acc2[g][nt][reg] * iz;
        }
    }
}

// ---------------- gathering loss: mean((q_norm - values[idx])^2) ----------------
__global__ __launch_bounds__(256) void gather_kernel(
    const float* __restrict__ query, const float* __restrict__ values,
    const int* __restrict__ idx, float* __restrict__ slot) {
    __shared__ float red[4];
    const int tid = threadIdx.x, w = tid >> 6, l = tid & 63;
    float acc = 0.f;
#pragma unroll
    for (int rr = 0; rr < 8; rr++) {
        int t = (blockIdx.x << 5) + w * 8 + rr;
        const float4* qr = (const float4*)(query + (size_t)t * C_DIM);
        float4 a = qr[l * 2], b = qr[l * 2 + 1];
        float ss = a.x * a.x + a.y * a.y + a.z * a.z + a.w * a.w +
                   b.x * b.x + b.y * b.y + b.z * b.z + b.w * b.w;
#pragma unroll
        for (int m = 1; m < 64; m <<= 1) ss += __shfl_xor(ss, m, 64);
        float inv = 1.0f / fmaxf(sqrtf(ss), 1e-12f);
        const float4* vr = (const float4*)(values + (size_t)idx[t] * C_DIM);
        float4 va = vr[l * 2], vb = vr[l * 2 + 1];
        float d;
        d = a.x * inv - va.x; acc += d * d;
        d = a.y * inv - va.y; acc += d * d;
        d = a.z * inv - va.z; acc += d * d;
        d = a.w * inv - va.w; acc += d * d;
        d = b.x * inv - vb.x; acc += d * d;
        d = b.y * inv - vb.y; acc += d * d;
        d = b.z * inv - vb.z; acc += d * d;
        d = b.w * inv - vb.w; acc += d * d;
    }
#pragma unroll
    for (int m = 1; m < 64; m <<= 1) acc += __shfl_xor(acc, m, 64);
    if (l == 0) red[w] = acc;
    __syncthreads();
    if (tid == 0)
        atomicAdd(slot, (red[0] + red[1] + red[2] + red[3]) * (1.0f / (32768.0f * 512.0f)));
}

extern "C" void kernel_launch(void* const* d_in, const int* in_sizes, int n_in,
                              void* d_out, int out_size, void* d_ws, size_t ws_size,
                              hipStream_t stream) {
    (void)in_sizes; (void)n_in; (void)out_size; (void)ws_size;
    const float* key    = (const float*)d_in[0];
    const float* query  = (const float*)d_in[1];
    const float* keysIn = (const float*)d_in[2];
    const float* valsIn = (const float*)d_in[3];
    float* out = (float*)d_out;

    unsigned short* keysFrag = (unsigned short*)d_ws;            // 512 KB
    unsigned short* valsFrag = keysFrag + 512 * 512;             // 512 KB
    int* idxBuf = (int*)(valsFrag + 512 * 512);                  // 128 KB

    float* outRQ   = out;                       // 16777216 floats
    float* scal    = out + 16777216;            // entropy, gathering, contrast
    float* keysOut = out + 16777219;            // 262144 floats
    float* valsOut = keysOut + 262144;          // 262144 floats

    hipMemsetAsync(scal, 0, 3 * sizeof(float), stream);
    hipMemcpyAsync(keysOut, keysIn, 262144 * sizeof(float), hipMemcpyDeviceToDevice, stream);
    hipMemcpyAsync(valsOut, valsIn, 262144 * sizeof(float), hipMemcpyDeviceToDevice, stream);

    pack_kernel<<<256, 256, 0, stream>>>(keysIn, valsIn, keysFrag, valsFrag);
    fused_kernel<<<1024, 512, 0, stream>>>(key, keysFrag, valsFrag, outRQ, scal, idxBuf);
    gather_kernel<<<1024, 256, 0, stream>>>(query, valsIn, idxBuf, scal + 1);
}

// Round 2
// 246.152 us; speedup vs baseline: 1.1351x; 1.1351x over previous
//
#include <hip/hip_runtime.h>

typedef short short8 __attribute__((ext_vector_type(8)));
typedef float floatx4 __attribute__((ext_vector_type(4)));

#define C_DIM 512
#define KQ_STRIDE 1040   // bytes per row of the LDS k/p tile (512*2 + 16 pad)

__device__ __forceinline__ unsigned short f2bf(float f) {
    unsigned u = __builtin_bit_cast(unsigned, f);
    u = u + 0x7fffu + ((u >> 16) & 1u);
    return (unsigned short)(u >> 16);
}

// ---------------- pack kernel: keys -> B-frag order (score GEMM), values -> B-frag order (PV GEMM)
// B fragment for mfma_f32_16x16x32_bf16: lane l holds B[k = (l>>4)*8 + j][n = l&15], j=0..7
// frag buffer index: ((kt*32 + NT)*64 + l)*8 + j   (kt: K/32 tile, NT: N/16 tile)
__global__ __launch_bounds__(256) void pack_kernel(
    const float* __restrict__ keys, const float* __restrict__ values,
    unsigned short* __restrict__ keysFrag, unsigned short* __restrict__ valsFrag) {
    int tid = blockIdx.x * 256 + threadIdx.x;      // 0..65535
    int e  = tid & 32767;
    int l  = e & 63;
    int NT = (e >> 6) & 31;
    int kt = e >> 11;                               // 0..15
    int li = l & 15, q4 = l >> 4;
    unsigned short tmp[8];
    if (tid < 32768) {
        // score GEMM: B[k][n] = keys[n][k], keys is [M, C] row-major
        const float* s = keys + (size_t)(NT * 16 + li) * C_DIM + kt * 32 + q4 * 8;
#pragma unroll
        for (int j = 0; j < 8; j++) tmp[j] = f2bf(s[j]);
        unsigned short* d = keysFrag + ((size_t)(kt * 32 + NT) * 64 + l) * 8;
        *(ushort4*)d       = make_ushort4(tmp[0], tmp[1], tmp[2], tmp[3]);
        *(ushort4*)(d + 4) = make_ushort4(tmp[4], tmp[5], tmp[6], tmp[7]);
    } else {
        // PV GEMM: B[k][n] = values[k][n], k indexes M
#pragma unroll
        for (int j = 0; j < 8; j++)
            tmp[j] = f2bf(values[(size_t)(kt * 32 + q4 * 8 + j) * C_DIM + NT * 16 + li]);
        unsigned short* d = valsFrag + ((size_t)(kt * 32 + NT) * 64 + l) * 8;
        *(ushort4*)d       = make_ushort4(tmp[0], tmp[1], tmp[2], tmp[3]);
        *(ushort4*)(d + 4) = make_ushort4(tmp[4], tmp[5], tmp[6], tmp[7]);
    }
}

// ---------------- fused main kernel: 64 rows per block, 512 threads (8 waves)
// Score GEMM + PV GEMM wave tile: 64 rows x 64 cols (cols [w*64, w*64+64)).
// Each B fragment is read exactly once per block.
__global__ __launch_bounds__(512, 4) void fused_kernel(
    const float* __restrict__ key,
    const float* __restrict__ query,
    const unsigned short* __restrict__ keysFrag,
    const unsigned short* __restrict__ valsFrag,
    const float* __restrict__ values,
    float* __restrict__ outRQ,
    float* __restrict__ scal) {   // [0]=entropy, [1]=gather, [2]=contrast
    __shared__ char kq[64 * KQ_STRIDE];      // k bf16 tile, later reused as p tile
    __shared__ float stats[8][64][6];        // [wave][row][m,z1,e1,z2,idx(int),pad]
    __shared__ float finals[64][2];          // [row][m1, 1/z1]
    __shared__ int   idxsh[64];
    __shared__ float gpart[8];

    const int tid = threadIdx.x;
    const int w  = tid >> 6;
    const int l  = tid & 63;
    const int li = l & 15;
    const int q4 = l >> 4;
    const int row0 = blockIdx.x << 6;

    // ---- phase 0: load 8 rows/wave, l2-normalize, write bf16 to LDS ----
#pragma unroll
    for (int it = 0; it < 2; it++) {
        int r = (w << 3) + (it << 2) + q4;                      // 16 lanes per row
        const float4* src = (const float4*)(key + (size_t)(row0 + r) * C_DIM);
        float4 v[8];
        float ss = 0.f;
#pragma unroll
        for (int i = 0; i < 8; i++) {
            v[i] = src[i * 16 + li];
            ss += v[i].x * v[i].x + v[i].y * v[i].y + v[i].z * v[i].z + v[i].w * v[i].w;
        }
#pragma unroll
        for (int m = 1; m < 16; m <<= 1) ss += __shfl_xor(ss, m, 64);
        float inv = 1.0f / fmaxf(sqrtf(ss), 1e-12f);
        char* dstrow = kq + r * KQ_STRIDE;
#pragma unroll
        for (int i = 0; i < 8; i++) {
            ushort4 b = make_ushort4(f2bf(v[i].x * inv), f2bf(v[i].y * inv),
                                     f2bf(v[i].z * inv), f2bf(v[i].w * inv));
            *(ushort4*)(dstrow + i * 128 + li * 8) = b;
        }
    }
    __syncthreads();

    // ---- phase 1: score GEMM, 64 rows x cols [w*64, +64), B prefetched one kt ahead ----
    floatx4 acc1[16];                        // [rg][nt]
#pragma unroll
    for (int i = 0; i < 16; i++) acc1[i] = (floatx4){0.f, 0.f, 0.f, 0.f};
    {
        const short8* kf = (const short8*)keysFrag;
        short8 bcur[4], bnxt[4];
#pragma unroll
        for (int nt = 0; nt < 4; nt++) bcur[nt] = kf[(size_t)((w * 4 + nt) * 64 + l)];
        for (int kt = 0; kt < 16; kt++) {
            if (kt < 15) {
#pragma unroll
                for (int nt = 0; nt < 4; nt++)
                    bnxt[nt] = kf[(size_t)(((kt + 1) * 32 + w * 4 + nt) * 64 + l)];
            }
            short8 a[4];
#pragma unroll
            for (int rg = 0; rg < 4; rg++)
                a[rg] = *(const short8*)(kq + (rg * 16 + li) * KQ_STRIDE + kt * 64 + q4 * 16);
#pragma unroll
            for (int rg = 0; rg < 4; rg++)
#pragma unroll
                for (int nt = 0; nt < 4; nt++)
                    acc1[rg * 4 + nt] = __builtin_amdgcn_mfma_f32_16x16x32_bf16(
                        a[rg], bcur[nt], acc1[rg * 4 + nt], 0, 0, 0);
#pragma unroll
            for (int nt = 0; nt < 4; nt++) bcur[nt] = bnxt[nt];
        }
    }

    // ---- phase 2: per-row partial stats. C layout: col = li, row = q4*4 + reg ----
#pragma unroll
    for (int rg = 0; rg < 4; rg++) {
#pragma unroll
        for (int reg = 0; reg < 4; reg++) {
            float m = acc1[rg * 4][reg];
            int bi = w * 64 + li;
#pragma unroll
            for (int nt = 1; nt < 4; nt++) {
                float s = acc1[rg * 4 + nt][reg];
                if (s > m) { m = s; bi = w * 64 + nt * 16 + li; }
            }
            float z1 = 0.f, e1 = 0.f, z2 = 0.f;
#pragma unroll
            for (int nt = 0; nt < 4; nt++) {
                float s = acc1[rg * 4 + nt][reg];
                float p = __expf(s - m);
                z1 += p; e1 += p * s; z2 += p * p;
            }
#pragma unroll
            for (int msk = 1; msk < 16; msk <<= 1) {
                float mo  = __shfl_xor(m,  msk, 64);
                float z1o = __shfl_xor(z1, msk, 64);
                float e1o = __shfl_xor(e1, msk, 64);
                float z2o = __shfl_xor(z2, msk, 64);
                int   bio = __shfl_xor(bi, msk, 64);
                if (mo > m) {
                    float sc = __expf(m - mo);
                    z1 = z1 * sc + z1o; e1 = e1 * sc + e1o; z2 = z2 * sc * sc + z2o;
                    m = mo; bi = bio;
                } else if (mo == m) {
                    z1 += z1o; e1 += e1o; z2 += z2o; bi = min(bi, bio);
                } else {
                    float sc = __expf(mo - m);
                    z1 += z1o * sc; e1 += e1o * sc; z2 += z2o * sc * sc;
                }
            }
            if (li == 0) {
                float* st = stats[w][rg * 16 + q4 * 4 + reg];
                st[0] = m; st[1] = z1; st[2] = e1; st[3] = z2;
                ((int*)st)[4] = bi;
            }
        }
    }
    __syncthreads();

    // ---- combine across 8 waves (wave 0 only) ----
    if (tid < 64) {
        int r = tid;
        const float* st0 = stats[0][r];
        float m = st0[0], z1 = st0[1], e1 = st0[2], z2 = st0[3];
        int bi = ((const int*)st0)[4];
#pragma unroll
        for (int p = 1; p < 8; p++) {
            const float* st = stats[p][r];
            float mo = st[0], z1o = st[1], e1o = st[2], z2o = st[3];
            int bio = ((const int*)st)[4];
            if (mo > m) {
                float sc = __expf(m - mo);
                z1 = z1 * sc + z1o; e1 = e1 * sc + e1o; z2 = z2 * sc * sc + z2o;
                m = mo; bi = bio;
            } else if (mo == m) {
                z1 += z1o; e1 += e1o; z2 += z2o; bi = min(bi, bio);
            } else {
                float sc = __expf(mo - m);
                z1 += z1o * sc; e1 += e1o * sc; z2 += z2o * sc * sc;
            }
        }
        finals[r][0] = m;
        finals[r][1] = 1.0f / z1;
        idxsh[r] = bi;
        float ent = m + __logf(z1) - e1 / z1;   // logZ - E[s]
        float con = __logf(z2);                  // -logp[idx] of logits = 2s
#pragma unroll
        for (int msk = 1; msk < 64; msk <<= 1) {
            ent += __shfl_xor(ent, msk, 64);
            con += __shfl_xor(con, msk, 64);
        }
        if (tid == 0) {
            atomicAdd(&scal[0], ent * (1.0f / 32768.0f));
            atomicAdd(&scal[2], con * (1.0f / 12800.0f));
        }
    }
    __syncthreads();

    // ---- phase 3: p = e^{s - m1} bf16, overwrite kq ----
#pragma unroll
    for (int rg = 0; rg < 4; rg++) {
#pragma unroll
        for (int reg = 0; reg < 4; reg++) {
            int r = rg * 16 + q4 * 4 + reg;
            float m1 = finals[r][0];
#pragma unroll
            for (int nt = 0; nt < 4; nt++) {
                float p = __expf(acc1[rg * 4 + nt][reg] - m1);
                int col = w * 64 + nt * 16 + li;
                *(unsigned short*)(kq + r * KQ_STRIDE + col * 2) = f2bf(p);
            }
        }
    }
    __syncthreads();

    // ---- phase 4: PV GEMM, 64 rows x out cols [w*64, +64) ----
    floatx4 acc2[16];
#pragma unroll
    for (int i = 0; i < 16; i++) acc2[i] = (floatx4){0.f, 0.f, 0.f, 0.f};
    {
        const short8* vf = (const short8*)valsFrag;
        short8 bcur[4], bnxt[4];
#pragma unroll
        for (int nt = 0; nt < 4; nt++) bcur[nt] = vf[(size_t)((w * 4 + nt) * 64 + l)];
        for (int kt = 0; kt < 16; kt++) {
            if (kt < 15) {
#pragma unroll
                for (int nt = 0; nt < 4; nt++)
                    bnxt[nt] = vf[(size_t)(((kt + 1) * 32 + w * 4 + nt) * 64 + l)];
            }
            short8 a[4];
#pragma unroll
            for (int rg = 0; rg < 4; rg++)
                a[rg] = *(const short8*)(kq + (rg * 16 + li) * KQ_STRIDE + kt * 64 + q4 * 16);
#pragma unroll
            for (int rg = 0; rg < 4; rg++)
#pragma unroll
                for (int nt = 0; nt < 4; nt++)
                    acc2[rg * 4 + nt] = __builtin_amdgcn_mfma_f32_16x16x32_bf16(
                        a[rg], bcur[nt], acc2[rg * 4 + nt], 0, 0, 0);
#pragma unroll
            for (int nt = 0; nt < 4; nt++) bcur[nt] = bnxt[nt];
        }
    }

    // ---- phase 5: scale by 1/Z1 and store ----
#pragma unroll
    for (int rg = 0; rg < 4; rg++) {
#pragma unroll
        for (int reg = 0; reg < 4; reg++) {
            int r = rg * 16 + q4 * 4 + reg;
            float iz = finals[r][1];
            float* orow = outRQ + (size_t)(row0 + r) * C_DIM + w * 64 + li;
#pragma unroll
            for (int nt = 0; nt < 4; nt++) orow[nt * 16] = acc2[rg * 4 + nt][reg] * iz;
        }
    }

    // ---- phase 6: fused gathering loss: mean((q_norm - values[idx])^2) ----
    float gacc = 0.f;
#pragma unroll
    for (int rr = 0; rr < 8; rr++) {
        int r = (w << 3) + rr;
        const float4* qr = (const float4*)(query + (size_t)(row0 + r) * C_DIM);
        float4 a = qr[l * 2], b = qr[l * 2 + 1];
        float ss = a.x * a.x + a.y * a.y + a.z * a.z + a.w * a.w +
                   b.x * b.x + b.y * b.y + b.z * b.z + b.w * b.w;
#pragma unroll
        for (int m = 1; m < 64; m <<= 1) ss += __shfl_xor(ss, m, 64);
        float inv = 1.0f / fmaxf(sqrtf(ss), 1e-12f);
        const float4* vr = (const float4*)(values + (size_t)idxsh[r] * C_DIM);
        float4 va = vr[l * 2], vb = vr[l * 2 + 1];
        float d;
        d = a.x * inv - va.x; gacc += d * d;
        d = a.y * inv - va.y; gacc += d * d;
        d = a.z * inv - va.z; gacc += d * d;
        d = a.w * inv - va.w; gacc += d * d;
        d = b.x * inv - vb.x; gacc += d * d;
        d = b.y * inv - vb.y; gacc += d * d;
        d = b.z * inv - vb.z; gacc += d * d;
        d = b.w * inv - vb.w; gacc += d * d;
    }
#pragma unroll
    for (int m = 1; m < 64; m <<= 1) gacc += __shfl_xor(gacc, m, 64);
    if (l == 0) gpart[w] = gacc;
    __syncthreads();
    if (tid == 0) {
        float s = 0.f;
#pragma unroll
        for (int i = 0; i < 8; i++) s += gpart[i];
        atomicAdd(&scal[1], s * (1.0f / (32768.0f * 512.0f)));
    }
}

extern "C" void kernel_launch(void* const* d_in, const int* in_sizes, int n_in,
                              void* d_out, int out_size, void* d_ws, size_t ws_size,
                              hipStream_t stream) {
    (void)in_sizes; (void)n_in; (void)out_size; (void)ws_size;
    const float* key    = (const float*)d_in[0];
    const float* query  = (const float*)d_in[1];
    const float* keysIn = (const float*)d_in[2];
    const float* valsIn = (const float*)d_in[3];
    float* out = (float*)d_out;

    unsigned short* keysFrag = (unsigned short*)d_ws;            // 512 KB
    unsigned short* valsFrag = keysFrag + 512 * 512;             // 512 KB

    float* outRQ   = out;                       // 16777216 floats
    float* scal    = out + 16777216;            // entropy, gathering, contrast
    float* keysOut = out + 16777219;            // 262144 floats
    float* valsOut = keysOut + 262144;          // 262144 floats

    hipMemsetAsync(scal, 0, 3 * sizeof(float), stream);
    hipMemcpyAsync(keysOut, keysIn, 262144 * sizeof(float), hipMemcpyDeviceToDevice, stream);
    hipMemcpyAsync(valsOut, valsIn, 262144 * sizeof(float), hipMemcpyDeviceToDevice, stream);

    pack_kernel<<<256, 256, 0, stream>>>(keysIn, valsIn, keysFrag, valsFrag);
    fused_kernel<<<512, 512, 0, stream>>>(key, query, keysFrag, valsFrag, valsIn, outRQ, scal);
}